// Round 5
// baseline (84.082 us; speedup 1.0000x reference)
//
#include <hip/hip_runtime.h>

#define NPTS 8192
#define DIM  32
#define TILE 128
#define TPB  256
#define NT   (NPTS / TILE)          /* 64 tiles per dim */
#define NBLK (NT * (NT + 1) / 2)    /* 2080 upper-tri blocks */
#define GRP  12                     /* padded fragment-group stride (floats): 48B -> 2-way banks (free) */

// codon index (dict order of CODON_TABLE) -> biosynthetic family id, -1 = stop.
// Families: 0 glutamate(E,Q,P,R), 1 aspartate(D,N,T,I,M,K), 2 serine(S,G,C),
// 3 pyruvate(A,V,L), 4 aromatic(F,Y,W), 5 histidine(H). K -> aspartate (overwrite order).
__device__ const int FID[64] = {
    4,4,3,3, 3,3,3,3, 1,1,1,1, 3,3,3,3,   // UUx CUx AUx GUx
    2,2,2,2, 0,0,0,0, 1,1,1,1, 3,3,3,3,   // UCx CCx ACx GCx
    4,4,-1,-1, 5,5,0,0, 1,1,1,1, 1,1,0,0, // UAx CAx AAx GAx
    2,2,-1,4, 0,0,0,0, 2,2,0,0, 2,2,2,2   // UGx CGx AGx GGx
};

// Per-point squared norm + family id + family histogram (for analytic counts).
// Stop codons get a unique negative id per position so equality tests never
// match (removes the fid>=0 compare in the hot epilogue); the i==j self-pair
// has dist 0 so it never contributes to sums anyway.
__global__ void prep_kernel(const float* __restrict__ x, const int* __restrict__ idx,
                            float* __restrict__ sq, int* __restrict__ fid,
                            int* __restrict__ cnts) {
    __shared__ int c[8];
    int tid = threadIdx.x;
    if (tid < 8) c[tid] = 0;
    __syncthreads();
    int gid = blockIdx.x * blockDim.x + tid;
    const float4* p = (const float4*)(x + (size_t)gid * DIM);
    float s = 0.f;
#pragma unroll
    for (int v = 0; v < 8; ++v) {
        float4 f = p[v];
        s += f.x * f.x + f.y * f.y + f.z * f.z + f.w * f.w;
    }
    sq[gid] = s;
    int f = FID[idx[gid] & 63];
    fid[gid] = (f >= 0) ? f : (-10 - gid);
    atomicAdd(&c[f < 0 ? 6 : f], 1);
    __syncthreads();
    if (tid < 7) atomicAdd(&cnts[tid], c[tid]);
}

// One 128x128 pair tile per block, upper-triangle blocks only, weight x2.
// 8x8 register micro-tile per thread; k-major LDS with 12-float fragment
// groups so the 16-lane A-fragment ds_read_b128s are 2-way (= conflict-free).
__global__ __launch_bounds__(TPB, 2) void pair_kernel(const float* __restrict__ x,
                                                      const float* __restrict__ sq,
                                                      const int* __restrict__ fid,
                                                      double* __restrict__ sums) {
    __shared__ float As[DIM][16 * GRP];
    __shared__ float Bs[DIM][16 * GRP];
    __shared__ float sqA[TILE], sqB[TILE];
    __shared__ int   fA[TILE],  fB[TILE];
    __shared__ double red[4][2];

    // linear block id -> upper-tri (I, J), J >= I. Offset(I) = I*NT - I*(I-1)/2
    int b = blockIdx.x;
    int I = (int)((2 * NT + 1 - sqrtf((float)((2 * NT + 1) * (2 * NT + 1) - 8 * b))) * 0.5f);
    if (I < 0) I = 0;
    if (I > NT - 1) I = NT - 1;
    while ((I + 1) * NT - (I + 1) * I / 2 <= b) ++I;
    while (I * NT - I * (I - 1) / 2 > b) --I;
    int J = I + (b - (I * NT - I * (I - 1) / 2));
    int I0 = I * TILE, J0 = J * TILE;

    int tid = threadIdx.x;
    {   // stage both tiles, transposing [pt][k] -> [k][group][elem].
        int pnt = tid >> 1, h = tid & 1;
        int col = (pnt >> 3) * GRP + (pnt & 7);
        const float4* srcA = (const float4*)(x + (size_t)(I0 + pnt) * DIM + h * 16);
        const float4* srcB = (const float4*)(x + (size_t)(J0 + pnt) * DIM + h * 16);
#pragma unroll
        for (int v = 0; v < 4; ++v) {
            float4 fa = srcA[v];
            float4 fb = srcB[v];
            int kb = h * 16 + v * 4;
            As[kb + 0][col] = fa.x; As[kb + 1][col] = fa.y;
            As[kb + 2][col] = fa.z; As[kb + 3][col] = fa.w;
            Bs[kb + 0][col] = fb.x; Bs[kb + 1][col] = fb.y;
            Bs[kb + 2][col] = fb.z; Bs[kb + 3][col] = fb.w;
        }
    }
    if (tid < TILE) { sqA[tid] = sq[I0 + tid]; fA[tid] = fid[I0 + tid]; }
    else { int t = tid - TILE; sqB[t] = sq[J0 + t]; fB[t] = fid[J0 + t]; }
    __syncthreads();

    int ti = tid & 15, tj = tid >> 4;
    int i0 = ti * 8, j0 = tj * 8;

    float acc[8][8];
#pragma unroll
    for (int ii = 0; ii < 8; ++ii)
#pragma unroll
        for (int jj = 0; jj < 8; ++jj) acc[ii][jj] = 0.f;

#pragma unroll
    for (int k = 0; k < DIM; ++k) {
        float4 a0 = *(const float4*)&As[k][ti * GRP];
        float4 a1 = *(const float4*)&As[k][ti * GRP + 4];
        float4 b0 = *(const float4*)&Bs[k][tj * GRP];
        float4 b1 = *(const float4*)&Bs[k][tj * GRP + 4];
        float a[8]  = {a0.x, a0.y, a0.z, a0.w, a1.x, a1.y, a1.z, a1.w};
        float bb[8] = {b0.x, b0.y, b0.z, b0.w, b1.x, b1.y, b1.z, b1.w};
#pragma unroll
        for (int ii = 0; ii < 8; ++ii)
#pragma unroll
            for (int jj = 0; jj < 8; ++jj)
                acc[ii][jj] = fmaf(a[ii], bb[jj], acc[ii][jj]);
    }

    float sqa[8], sqb[8];
    int fa[8], fb[8];
#pragma unroll
    for (int u = 0; u < 8; ++u) {
        sqa[u] = sqA[i0 + u]; sqb[u] = sqB[j0 + u];
        fa[u]  = fA[i0 + u];  fb[u]  = fB[j0 + u];
    }

    bool diagblk = (I == J);
    float s_all = 0.f, s_same = 0.f;
#pragma unroll
    for (int ii = 0; ii < 8; ++ii) {
#pragma unroll
        for (int jj = 0; jj < 8; ++jj) {
            float sqd = sqa[ii] + sqb[jj] - 2.f * acc[ii][jj];
            float dst = sqrtf(fmaxf(sqd, 0.f));  // sqrt(0)=0 covers the where()
            if (diagblk && (i0 + ii) >= (j0 + jj)) dst = 0.f; // strict upper on diag
            s_all += dst;
            s_same += (fa[ii] == fb[jj]) ? dst : 0.f;
        }
    }
    s_all *= 2.f;   // symmetry weight
    s_same *= 2.f;

#pragma unroll
    for (int off = 32; off >= 1; off >>= 1) {
        s_all  += __shfl_xor(s_all, off);
        s_same += __shfl_xor(s_same, off);
    }
    int wv = tid >> 6;
    if ((tid & 63) == 0) { red[wv][0] = (double)s_all; red[wv][1] = (double)s_same; }
    __syncthreads();
    if (tid == 0) {
        double ta = red[0][0] + red[1][0] + red[2][0] + red[3][0];
        double ts = red[0][1] + red[1][1] + red[2][1] + red[3][1];
        atomicAdd(&sums[0], ta);
        atomicAdd(&sums[1], ts);
    }
}

__global__ void final_kernel(const double* __restrict__ sums,
                             const int* __restrict__ cnts,
                             float* __restrict__ out) {
    double csame = 0.0;
#pragma unroll
    for (int f = 0; f < 6; ++f) csame += (double)cnts[f] * (double)cnts[f];
    double cdiff = (double)NPTS * (double)NPTS - csame;
    double s_all = sums[0], s_same = sums[1];
    double same_mean = s_same / (csame + 1e-10);
    double diff_mean = (s_all - s_same) / (cdiff + 1e-10);
    double loss = same_mean - 0.5 * diff_mean + 1.0;
    out[0] = (float)(loss > 0.0 ? loss : 0.0);
}

extern "C" void kernel_launch(void* const* d_in, const int* in_sizes, int n_in,
                              void* d_out, int out_size, void* d_ws, size_t ws_size,
                              hipStream_t stream) {
    const float* x  = (const float*)d_in[0];   // (16,512,32) f32 -> 8192x32
    const int* idx  = (const int*)d_in[1];     // (16,512) int
    float* out      = (float*)d_out;

    // ws: [0..16) double sums[2]; [16..48) int cnts[8]; [64..) sq[8192] f32; then fid[8192] i32
    double* sums = (double*)d_ws;
    int* cnts    = (int*)((char*)d_ws + 16);
    float* sq    = (float*)((char*)d_ws + 64);
    int* fid     = (int*)((char*)d_ws + 64 + NPTS * sizeof(float));

    hipMemsetAsync(d_ws, 0, 64, stream);
    prep_kernel<<<NPTS / TPB, TPB, 0, stream>>>(x, idx, sq, fid, cnts);
    pair_kernel<<<NBLK, TPB, 0, stream>>>(x, sq, fid, sums);
    final_kernel<<<1, 1, 0, stream>>>(sums, cnts, out);
}

// Round 6
// 75.419 us; speedup vs baseline: 1.1149x; 1.1149x over previous
//
#include <hip/hip_runtime.h>

#define NPTS 8192
#define DIM  32
#define TILE 128
#define TPB  256
#define NT   (NPTS / TILE)          /* 64 tiles per dim */
#define NBLK (NT * (NT + 1) / 2)    /* 2080 upper-tri blocks */
#define ROWS 72                     /* shorts per LDS row: 32 hi | 32 lo | 8 pad (144B stride, bank-even) */

typedef __attribute__((ext_vector_type(8))) short short8;   // 8 bf16 = 4 VGPR (MFMA A/B frag)
typedef __attribute__((ext_vector_type(4))) float floatx4;  // MFMA C/D frag

// codon index (dict order of CODON_TABLE) -> biosynthetic family id, -1 = stop.
__device__ const int FID[64] = {
    4,4,3,3, 3,3,3,3, 1,1,1,1, 3,3,3,3,   // UUx CUx AUx GUx
    2,2,2,2, 0,0,0,0, 1,1,1,1, 3,3,3,3,   // UCx CCx ACx GCx
    4,4,-1,-1, 5,5,0,0, 1,1,1,1, 1,1,0,0, // UAx CAx AAx GAx
    2,2,-1,4, 0,0,0,0, 2,2,0,0, 2,2,2,2   // UGx CGx AGx GGx
};

__device__ __forceinline__ unsigned short bf16_rne(float f) {
    unsigned u = __float_as_uint(f);
    unsigned r = u + 0x7FFFu + ((u >> 16) & 1u);   // round-to-nearest-even
    return (unsigned short)(r >> 16);
}
__device__ __forceinline__ float bf16_f(unsigned short h) {
    return __uint_as_float(((unsigned)h) << 16);
}

// Per-point squared norm (exact f32) + family id + family histogram.
__global__ void prep_kernel(const float* __restrict__ x, const int* __restrict__ idx,
                            float* __restrict__ sq, int* __restrict__ fid,
                            int* __restrict__ cnts) {
    __shared__ int c[8];
    int tid = threadIdx.x;
    if (tid < 8) c[tid] = 0;
    __syncthreads();
    int gid = blockIdx.x * blockDim.x + tid;
    const float4* p = (const float4*)(x + (size_t)gid * DIM);
    float s = 0.f;
#pragma unroll
    for (int v = 0; v < 8; ++v) {
        float4 f = p[v];
        s += f.x * f.x + f.y * f.y + f.z * f.z + f.w * f.w;
    }
    sq[gid] = s;
    int f = FID[idx[gid] & 63];
    fid[gid] = (f >= 0) ? f : (-10 - gid);   // unique negatives: equality never matches
    atomicAdd(&c[f < 0 ? 6 : f], 1);
    __syncthreads();
    if (tid < 7) atomicAdd(&cnts[tid], c[tid]);
}

// 128x128 pair tile per block via bf16 hi/lo-split MFMA (3 passes, exact to ~1e-5).
// 4 waves; wave w owns rows [w*32, w*32+32) x all 128 cols = 2x8 16x16 subtiles.
__global__ __launch_bounds__(TPB, 2) void pair_kernel(const float* __restrict__ x,
                                                      const float* __restrict__ sq,
                                                      const int* __restrict__ fid,
                                                      double* __restrict__ sums) {
    __shared__ __align__(16) short Ash[TILE][ROWS];
    __shared__ __align__(16) short Bsh[TILE][ROWS];
    __shared__ double red[4][2];

    // linear block id -> upper-tri (I, J), J >= I
    int b = blockIdx.x;
    int I = (int)((2 * NT + 1 - sqrtf((float)((2 * NT + 1) * (2 * NT + 1) - 8 * b))) * 0.5f);
    if (I < 0) I = 0;
    if (I > NT - 1) I = NT - 1;
    while ((I + 1) * NT - (I + 1) * I / 2 <= b) ++I;
    while (I * NT - I * (I - 1) / 2 > b) --I;
    int J = I + (b - (I * NT - I * (I - 1) / 2));
    int I0 = I * TILE, J0 = J * TILE;

    int tid = threadIdx.x;
    {   // stage both tiles: f32 -> bf16 hi/lo into LDS. thread = (point, half).
        int pnt = tid >> 1, h = tid & 1;
        const floatx4* srcA = (const floatx4*)(x + (size_t)(I0 + pnt) * DIM + h * 16);
        const floatx4* srcB = (const floatx4*)(x + (size_t)(J0 + pnt) * DIM + h * 16);
        float f[16];
#pragma unroll
        for (int side = 0; side < 2; ++side) {
            const floatx4* src = side ? srcB : srcA;
            short* dst = side ? &Bsh[pnt][0] : &Ash[pnt][0];
            *(floatx4*)&f[0]  = src[0];
            *(floatx4*)&f[4]  = src[1];
            *(floatx4*)&f[8]  = src[2];
            *(floatx4*)&f[12] = src[3];
            short8 hi0, hi1, lo0, lo1;
#pragma unroll
            for (int i = 0; i < 8; ++i) {
                unsigned short hb = bf16_rne(f[i]);
                unsigned short lb = bf16_rne(f[i] - bf16_f(hb));
                hi0[i] = (short)hb; lo0[i] = (short)lb;
            }
#pragma unroll
            for (int i = 0; i < 8; ++i) {
                unsigned short hb = bf16_rne(f[8 + i]);
                unsigned short lb = bf16_rne(f[8 + i] - bf16_f(hb));
                hi1[i] = (short)hb; lo1[i] = (short)lb;
            }
            *(short8*)&dst[h * 16]          = hi0;
            *(short8*)&dst[h * 16 + 8]      = hi1;
            *(short8*)&dst[32 + h * 16]     = lo0;
            *(short8*)&dst[32 + h * 16 + 8] = lo1;
        }
    }
    __syncthreads();

    int lane = tid & 63, w = tid >> 6;
    int r16 = lane & 15, kg = lane >> 4;   // M/N index, k-group

    // A fragments (held): 2 row-subtiles x {hi,lo}
    short8 ah[2], al[2];
#pragma unroll
    for (int i = 0; i < 2; ++i) {
        int row = w * 32 + i * 16 + r16;
        ah[i] = *(const short8*)&Ash[row][kg * 8];
        al[i] = *(const short8*)&Ash[row][32 + kg * 8];
    }

    floatx4 acc[2][8];
#pragma unroll
    for (int i = 0; i < 2; ++i)
#pragma unroll
        for (int j = 0; j < 8; ++j) acc[i][j] = (floatx4)(0.f);

#pragma unroll
    for (int j = 0; j < 8; ++j) {
        int rowb = j * 16 + r16;
        short8 bh = *(const short8*)&Bsh[rowb][kg * 8];
        short8 bl = *(const short8*)&Bsh[rowb][32 + kg * 8];
#pragma unroll
        for (int i = 0; i < 2; ++i) {
            acc[i][j] = __builtin_amdgcn_mfma_f32_16x16x32_bf16(ah[i], bh, acc[i][j], 0, 0, 0);
            acc[i][j] = __builtin_amdgcn_mfma_f32_16x16x32_bf16(ah[i], bl, acc[i][j], 0, 0, 0);
            acc[i][j] = __builtin_amdgcn_mfma_f32_16x16x32_bf16(al[i], bh, acc[i][j], 0, 0, 0);
        }
    }

    // Epilogue. C/D layout (HW-verified): col = lane&15, row = (lane>>4)*4 + reg.
    float sqa[2][4]; int fa[2][4];
#pragma unroll
    for (int i = 0; i < 2; ++i)
#pragma unroll
        for (int r = 0; r < 4; ++r) {
            int row = I0 + w * 32 + i * 16 + kg * 4 + r;
            sqa[i][r] = sq[row]; fa[i][r] = fid[row];
        }
    float sqb[8]; int fb[8];
#pragma unroll
    for (int j = 0; j < 8; ++j) {
        int col = J0 + j * 16 + r16;
        sqb[j] = sq[col]; fb[j] = fid[col];
    }

    bool diagblk = (I == J);
    float s_all = 0.f, s_same = 0.f;
#pragma unroll
    for (int j = 0; j < 8; ++j) {
#pragma unroll
        for (int i = 0; i < 2; ++i) {
#pragma unroll
            for (int r = 0; r < 4; ++r) {
                float sqd = sqa[i][r] + sqb[j] - 2.f * acc[i][j][r];
                float dst = sqrtf(fmaxf(sqd, 0.f));
                if (diagblk) {
                    int lrow = w * 32 + i * 16 + kg * 4 + r;
                    int lcol = j * 16 + r16;
                    if (lrow >= lcol) dst = 0.f;   // strict upper triangle on diag blocks
                }
                s_all += dst;
                s_same += (fa[i][r] == fb[j]) ? dst : 0.f;
            }
        }
    }
    s_all *= 2.f;   // symmetry weight
    s_same *= 2.f;

#pragma unroll
    for (int off = 32; off >= 1; off >>= 1) {
        s_all  += __shfl_xor(s_all, off);
        s_same += __shfl_xor(s_same, off);
    }
    if ((tid & 63) == 0) { red[w][0] = (double)s_all; red[w][1] = (double)s_same; }
    __syncthreads();
    if (tid == 0) {
        double ta = red[0][0] + red[1][0] + red[2][0] + red[3][0];
        double ts = red[0][1] + red[1][1] + red[2][1] + red[3][1];
        atomicAdd(&sums[0], ta);
        atomicAdd(&sums[1], ts);
    }
}

__global__ void final_kernel(const double* __restrict__ sums,
                             const int* __restrict__ cnts,
                             float* __restrict__ out) {
    double csame = 0.0;
#pragma unroll
    for (int f = 0; f < 6; ++f) csame += (double)cnts[f] * (double)cnts[f];
    double cdiff = (double)NPTS * (double)NPTS - csame;
    double s_all = sums[0], s_same = sums[1];
    double same_mean = s_same / (csame + 1e-10);
    double diff_mean = (s_all - s_same) / (cdiff + 1e-10);
    double loss = same_mean - 0.5 * diff_mean + 1.0;
    out[0] = (float)(loss > 0.0 ? loss : 0.0);
}

extern "C" void kernel_launch(void* const* d_in, const int* in_sizes, int n_in,
                              void* d_out, int out_size, void* d_ws, size_t ws_size,
                              hipStream_t stream) {
    const float* x  = (const float*)d_in[0];   // (16,512,32) f32 -> 8192x32
    const int* idx  = (const int*)d_in[1];     // (16,512) int
    float* out      = (float*)d_out;

    // ws: [0..16) double sums[2]; [16..48) int cnts[8]; [64..) sq[8192] f32; then fid[8192] i32
    double* sums = (double*)d_ws;
    int* cnts    = (int*)((char*)d_ws + 16);
    float* sq    = (float*)((char*)d_ws + 64);
    int* fid     = (int*)((char*)d_ws + 64 + NPTS * sizeof(float));

    hipMemsetAsync(d_ws, 0, 64, stream);
    prep_kernel<<<NPTS / TPB, TPB, 0, stream>>>(x, idx, sq, fid, cnts);
    pair_kernel<<<NBLK, TPB, 0, stream>>>(x, sq, fid, sums);
    final_kernel<<<1, 1, 0, stream>>>(sums, cnts, out);
}

// Round 7
// 45.551 us; speedup vs baseline: 1.8459x; 1.6557x over previous
//
#include <hip/hip_runtime.h>

#define NPTS 8192
#define DIM  32
#define TILE 128
#define TPB  256
#define NT   (NPTS / TILE)          /* 64 tiles per dim */
#define NBLK (NT * (NT + 1) / 2)    /* 2080 upper-tri blocks */
#define ROWS 72                     /* shorts per LDS row: 32 hi | 32 lo | 8 pad (144B stride) */

typedef __attribute__((ext_vector_type(8))) short short8;   // 8 bf16 = 4 VGPR (MFMA A/B frag)
typedef __attribute__((ext_vector_type(4))) float floatx4;  // MFMA C/D frag

// codon index (dict order of CODON_TABLE) -> biosynthetic family id, -1 = stop.
__device__ const int FID[64] = {
    4,4,3,3, 3,3,3,3, 1,1,1,1, 3,3,3,3,   // UUx CUx AUx GUx
    2,2,2,2, 0,0,0,0, 1,1,1,1, 3,3,3,3,   // UCx CCx ACx GCx
    4,4,-1,-1, 5,5,0,0, 1,1,1,1, 1,1,0,0, // UAx CAx AAx GAx
    2,2,-1,4, 0,0,0,0, 2,2,0,0, 2,2,2,2   // UGx CGx AGx GGx
};

__device__ __forceinline__ unsigned short bf16_rne(float f) {
    unsigned u = __float_as_uint(f);
    unsigned r = u + 0x7FFFu + ((u >> 16) & 1u);   // round-to-nearest-even
    return (unsigned short)(r >> 16);
}
__device__ __forceinline__ float bf16_f(unsigned short h) {
    return __uint_as_float(((unsigned)h) << 16);
}

// Per-point squared norm (exact f32) + family id + family histogram.
__global__ void prep_kernel(const float* __restrict__ x, const int* __restrict__ idx,
                            float* __restrict__ sq, int* __restrict__ fid,
                            int* __restrict__ cnts) {
    __shared__ int c[8];
    int tid = threadIdx.x;
    if (tid < 8) c[tid] = 0;
    __syncthreads();
    int gid = blockIdx.x * blockDim.x + tid;
    const float4* p = (const float4*)(x + (size_t)gid * DIM);
    float s = 0.f;
#pragma unroll
    for (int v = 0; v < 8; ++v) {
        float4 f = p[v];
        s += f.x * f.x + f.y * f.y + f.z * f.z + f.w * f.w;
    }
    sq[gid] = s;
    int f = FID[idx[gid] & 63];
    fid[gid] = (f >= 0) ? f : (-10 - gid);   // unique negatives: equality never matches
    atomicAdd(&c[f < 0 ? 6 : f], 1);
    __syncthreads();
    if (tid < 7) atomicAdd(&cnts[tid], c[tid]);
}

// 128x128 pair tile per block via bf16 hi/lo-split MFMA (3 passes, exact to ~1e-5).
// 4 waves; wave w owns rows [w*32, w*32+32) x all 128 cols = 2x8 16x16 subtiles.
// Ends with per-block partial-sum STORES (no atomics — the R6 floor was 4160
// serialized cross-XCD f64 atomics on one cache line).
__global__ __launch_bounds__(TPB, 2) void pair_kernel(const float* __restrict__ x,
                                                      const float* __restrict__ sq,
                                                      const int* __restrict__ fid,
                                                      double* __restrict__ partials) {
    __shared__ __align__(16) short Ash[TILE][ROWS];
    __shared__ __align__(16) short Bsh[TILE][ROWS];
    __shared__ double red[4][2];

    // linear block id -> upper-tri (I, J), J >= I
    int b = blockIdx.x;
    int I = (int)((2 * NT + 1 - sqrtf((float)((2 * NT + 1) * (2 * NT + 1) - 8 * b))) * 0.5f);
    if (I < 0) I = 0;
    if (I > NT - 1) I = NT - 1;
    while ((I + 1) * NT - (I + 1) * I / 2 <= b) ++I;
    while (I * NT - I * (I - 1) / 2 > b) --I;
    int J = I + (b - (I * NT - I * (I - 1) / 2));
    int I0 = I * TILE, J0 = J * TILE;

    int tid = threadIdx.x;
    {   // stage both tiles: f32 -> bf16 hi/lo into LDS. thread = (point, half).
        int pnt = tid >> 1, h = tid & 1;
        const floatx4* srcA = (const floatx4*)(x + (size_t)(I0 + pnt) * DIM + h * 16);
        const floatx4* srcB = (const floatx4*)(x + (size_t)(J0 + pnt) * DIM + h * 16);
        float f[16];
#pragma unroll
        for (int side = 0; side < 2; ++side) {
            const floatx4* src = side ? srcB : srcA;
            short* dst = side ? &Bsh[pnt][0] : &Ash[pnt][0];
            *(floatx4*)&f[0]  = src[0];
            *(floatx4*)&f[4]  = src[1];
            *(floatx4*)&f[8]  = src[2];
            *(floatx4*)&f[12] = src[3];
            short8 hi0, hi1, lo0, lo1;
#pragma unroll
            for (int i = 0; i < 8; ++i) {
                unsigned short hb = bf16_rne(f[i]);
                unsigned short lb = bf16_rne(f[i] - bf16_f(hb));
                hi0[i] = (short)hb; lo0[i] = (short)lb;
            }
#pragma unroll
            for (int i = 0; i < 8; ++i) {
                unsigned short hb = bf16_rne(f[8 + i]);
                unsigned short lb = bf16_rne(f[8 + i] - bf16_f(hb));
                hi1[i] = (short)hb; lo1[i] = (short)lb;
            }
            *(short8*)&dst[h * 16]          = hi0;
            *(short8*)&dst[h * 16 + 8]      = hi1;
            *(short8*)&dst[32 + h * 16]     = lo0;
            *(short8*)&dst[32 + h * 16 + 8] = lo1;
        }
    }
    __syncthreads();

    int lane = tid & 63, w = tid >> 6;
    int r16 = lane & 15, kg = lane >> 4;   // M/N index, k-group

    // A fragments (held): 2 row-subtiles x {hi,lo}
    short8 ah[2], al[2];
#pragma unroll
    for (int i = 0; i < 2; ++i) {
        int row = w * 32 + i * 16 + r16;
        ah[i] = *(const short8*)&Ash[row][kg * 8];
        al[i] = *(const short8*)&Ash[row][32 + kg * 8];
    }

    floatx4 acc[2][8];
#pragma unroll
    for (int i = 0; i < 2; ++i)
#pragma unroll
        for (int j = 0; j < 8; ++j) acc[i][j] = (floatx4)(0.f);

#pragma unroll
    for (int j = 0; j < 8; ++j) {
        int rowb = j * 16 + r16;
        short8 bh = *(const short8*)&Bsh[rowb][kg * 8];
        short8 bl = *(const short8*)&Bsh[rowb][32 + kg * 8];
#pragma unroll
        for (int i = 0; i < 2; ++i) {
            acc[i][j] = __builtin_amdgcn_mfma_f32_16x16x32_bf16(ah[i], bh, acc[i][j], 0, 0, 0);
            acc[i][j] = __builtin_amdgcn_mfma_f32_16x16x32_bf16(ah[i], bl, acc[i][j], 0, 0, 0);
            acc[i][j] = __builtin_amdgcn_mfma_f32_16x16x32_bf16(al[i], bh, acc[i][j], 0, 0, 0);
        }
    }

    // Epilogue. C/D layout (HW-verified): col = lane&15, row = (lane>>4)*4 + reg.
    float sqa[2][4]; int fa[2][4];
#pragma unroll
    for (int i = 0; i < 2; ++i)
#pragma unroll
        for (int r = 0; r < 4; ++r) {
            int row = I0 + w * 32 + i * 16 + kg * 4 + r;
            sqa[i][r] = sq[row]; fa[i][r] = fid[row];
        }
    float sqb[8]; int fb[8];
#pragma unroll
    for (int j = 0; j < 8; ++j) {
        int col = J0 + j * 16 + r16;
        sqb[j] = sq[col]; fb[j] = fid[col];
    }

    bool diagblk = (I == J);
    float s_all = 0.f, s_same = 0.f;
#pragma unroll
    for (int j = 0; j < 8; ++j) {
#pragma unroll
        for (int i = 0; i < 2; ++i) {
#pragma unroll
            for (int r = 0; r < 4; ++r) {
                float sqd = sqa[i][r] + sqb[j] - 2.f * acc[i][j][r];
                float dst = sqrtf(fmaxf(sqd, 0.f));
                if (diagblk) {
                    int lrow = w * 32 + i * 16 + kg * 4 + r;
                    int lcol = j * 16 + r16;
                    if (lrow >= lcol) dst = 0.f;   // strict upper triangle on diag blocks
                }
                s_all += dst;
                s_same += (fa[i][r] == fb[j]) ? dst : 0.f;
            }
        }
    }
    s_all *= 2.f;   // symmetry weight
    s_same *= 2.f;

#pragma unroll
    for (int off = 32; off >= 1; off >>= 1) {
        s_all  += __shfl_xor(s_all, off);
        s_same += __shfl_xor(s_same, off);
    }
    if ((tid & 63) == 0) { red[w][0] = (double)s_all; red[w][1] = (double)s_same; }
    __syncthreads();
    if (tid == 0) {
        partials[2 * b]     = red[0][0] + red[1][0] + red[2][0] + red[3][0];
        partials[2 * b + 1] = red[0][1] + red[1][1] + red[2][1] + red[3][1];
    }
}

// One block: fixed-order tree reduce of 2080x2 doubles + final loss. Deterministic.
__global__ void reduce_kernel(const double* __restrict__ partials,
                              const int* __restrict__ cnts,
                              float* __restrict__ out) {
    __shared__ double sh[4][2];
    int tid = threadIdx.x;
    double ta = 0.0, ts = 0.0;
    for (int i = tid; i < NBLK; i += TPB) {
        ta += partials[2 * i];
        ts += partials[2 * i + 1];
    }
#pragma unroll
    for (int off = 32; off >= 1; off >>= 1) {
        ta += __shfl_xor(ta, off);
        ts += __shfl_xor(ts, off);
    }
    if ((tid & 63) == 0) { sh[tid >> 6][0] = ta; sh[tid >> 6][1] = ts; }
    __syncthreads();
    if (tid == 0) {
        double s_all  = sh[0][0] + sh[1][0] + sh[2][0] + sh[3][0];
        double s_same = sh[0][1] + sh[1][1] + sh[2][1] + sh[3][1];
        double csame = 0.0;
#pragma unroll
        for (int f = 0; f < 6; ++f) csame += (double)cnts[f] * (double)cnts[f];
        double cdiff = (double)NPTS * (double)NPTS - csame;
        double same_mean = s_same / (csame + 1e-10);
        double diff_mean = (s_all - s_same) / (cdiff + 1e-10);
        double loss = same_mean - 0.5 * diff_mean + 1.0;
        out[0] = (float)(loss > 0.0 ? loss : 0.0);
    }
}

extern "C" void kernel_launch(void* const* d_in, const int* in_sizes, int n_in,
                              void* d_out, int out_size, void* d_ws, size_t ws_size,
                              hipStream_t stream) {
    const float* x  = (const float*)d_in[0];   // (16,512,32) f32 -> 8192x32
    const int* idx  = (const int*)d_in[1];     // (16,512) int
    float* out      = (float*)d_out;

    // ws layout: [0..16) unused; [16..48) int cnts[8]; [64..33344) double partials[2*NBLK];
    //            [33344..66112) f32 sq[8192]; [66112..98880) i32 fid[8192]
    int* cnts        = (int*)((char*)d_ws + 16);
    double* partials = (double*)((char*)d_ws + 64);
    float* sq        = (float*)((char*)d_ws + 64 + NBLK * 2 * sizeof(double));
    int* fid         = (int*)((char*)d_ws + 64 + NBLK * 2 * sizeof(double) + NPTS * sizeof(float));

    hipMemsetAsync(d_ws, 0, 64, stream);   // zero cnts
    prep_kernel<<<NPTS / TPB, TPB, 0, stream>>>(x, idx, sq, fid, cnts);
    pair_kernel<<<NBLK, TPB, 0, stream>>>(x, sq, fid, partials);
    reduce_kernel<<<1, TPB, 0, stream>>>(partials, cnts, out);
}